// Round 1
// baseline (3332.717 us; speedup 1.0000x reference)
//
#include <hip/hip_runtime.h>
#include <hip/hip_fp16.h>

typedef unsigned int u32;
typedef unsigned short u16;
typedef _Float16 h2v __attribute__((ext_vector_type(2)));
typedef short short8 __attribute__((ext_vector_type(8)));
typedef float f32x4 __attribute__((ext_vector_type(4)));

#define MINN 1e-15f

__device__ __forceinline__ float wred(float v){
  #pragma unroll
  for (int m = 32; m > 0; m >>= 1) v += __shfl_xor(v, m, 64);
  return v;
}
__device__ __forceinline__ float bf2f(u32 lo16){ u32 u = lo16 << 16; return __builtin_bit_cast(float, u); }
__device__ __forceinline__ u16 f2bf(float f){
  u32 u = __builtin_bit_cast(u32, f);
  u32 r = (u + 0x7fffu + ((u >> 16) & 1u)) >> 16;
  return (u16)r;
}
__device__ __forceinline__ u16 f16b(float x){ __half h = __float2half(x); return __builtin_bit_cast(u16, h); }
__device__ __forceinline__ u32 pkh(float a, float b){
  u32 lo = f16b(a), hi = f16b(b);
  return lo | (hi << 16);
}
__device__ __forceinline__ float fdot2_(u32 a, u32 b, float c){
  return __builtin_amdgcn_fdot2(__builtin_bit_cast(h2v, a), __builtin_bit_cast(h2v, b), c, false);
}
__device__ __forceinline__ float tanh_fast(float x){
  float e = __expf(-2.f * fabsf(x));
  float t = (1.f - e) / (1.f + e);
  return x < 0.f ? -t : t;
}
__device__ __forceinline__ float artanh_c(float x){
  x = fminf(fmaxf(x, -1.f + 1e-5f), 1.f - 1e-5f);
  return 0.5f * __logf((1.f + x) / (1.f - x));
}
__device__ __forceinline__ float sigm(float x){ return 1.f / (1.f + __expf(-x)); }

// ---------------- weight repack: W' (fp16 pairs, k-major) -------------------
// gate cols: W'[k][col] = W_all[col&511][ (col>>9)*512 + k ],  col in [0,2048)
// d cols   : W'd[k][j]  = W_d[j][k]
__global__ void k_pack_w(const float* __restrict__ Wall, const float* __restrict__ Wd,
                         uint4* __restrict__ WG, uint4* __restrict__ WDP){
  int i = blockIdx.x * 256 + threadIdx.x;
  if (i < 128 * 1024) {
    int kp = i >> 10, c2 = i & 1023;
    int col0 = c2 * 2, col1 = col0 + 1;
    int k0 = kp * 4;
    const float* b0 = Wall + (size_t)(col0 & 511) * 2048 + (col0 >> 9) * 512 + k0;
    const float* b1 = Wall + (size_t)(col1 & 511) * 2048 + (col1 >> 9) * 512 + k0;
    uint4 o;
    o.x = pkh(b0[0], b0[1]); o.y = pkh(b1[0], b1[1]);
    o.z = pkh(b0[2], b0[3]); o.w = pkh(b1[2], b1[3]);
    WG[i] = o;
  } else {
    int e = i - 128 * 1024;
    if (e < 64 * 512) {
      int kq = e >> 9, j = e & 511;
      const float* b = Wd + (size_t)j * 512 + kq * 8;
      uint4 o;
      o.x = pkh(b[0], b[1]); o.y = pkh(b[2], b[3]);
      o.z = pkh(b[4], b[5]); o.w = pkh(b[6], b[7]);
      WDP[e] = o;
    }
  }
}

// ---------------- x -> bf16 + per-row |x|^2 --------------------------------
__global__ void k_convert_x(const float* __restrict__ X, u16* __restrict__ Xb, float* __restrict__ xn2){
  int r = blockIdx.x, t = threadIdx.x;
  const float* row = X + (size_t)r * 512;
  float v0 = row[t], v1 = row[t + 256];
  Xb[(size_t)r * 512 + t] = f2bf(v0);
  Xb[(size_t)r * 512 + t + 256] = f2bf(v1);
  float s = wred(v0 * v0 + v1 * v1);
  __shared__ float p[4];
  if ((t & 63) == 0) p[t >> 6] = s;
  __syncthreads();
  if (t == 0) xn2[r] = p[0] + p[1] + p[2] + p[3];
}

__global__ void k_convert_u(const float* __restrict__ U, u16* __restrict__ Ub){
  int i = blockIdx.x * 256 + threadIdx.x;
  Ub[i] = f2bf(U[i]);
}

// ---------------- mxU = X @ U^T, bf16 MFMA, C = A*B^T ----------------------
// A [8192,512] bf16 row-major, B [2048,512] bf16 row-major ([N][K]), C [8192,2048] bf16
__global__ void __launch_bounds__(256) k_gemm(const u16* __restrict__ A, const u16* __restrict__ B,
                                              u16* __restrict__ C){
  __shared__ u16 Al[128 * 32];
  __shared__ u16 Bl[128 * 32];
  int t = threadIdx.x;
  int bn = blockIdx.x, bm = blockIdx.y;
  int w = t >> 6, l = t & 63;
  int wr = w >> 1, wc = w & 1;
  f32x4 zero = {0.f, 0.f, 0.f, 0.f};
  f32x4 acc[4][4];
  #pragma unroll
  for (int m = 0; m < 4; ++m)
    #pragma unroll
    for (int n = 0; n < 4; ++n) acc[m][n] = zero;

  for (int kt = 0; kt < 16; ++kt) {
    #pragma unroll
    for (int i = 0; i < 2; ++i) {
      int off = t + i * 256;           // 16B chunks
      int r = off >> 2, ch = off & 3;
      *(uint4*)&Al[(size_t)off * 8] = *(const uint4*)(A + (size_t)(bm * 128 + r) * 512 + kt * 32 + ch * 8);
      *(uint4*)&Bl[(size_t)off * 8] = *(const uint4*)(B + (size_t)(bn * 128 + r) * 512 + kt * 32 + ch * 8);
    }
    __syncthreads();
    int ko = (l >> 4) * 8;
    short8 af[4], bfr[4];
    #pragma unroll
    for (int m = 0; m < 4; ++m) af[m] = *(const short8*)&Al[(wr * 64 + m * 16 + (l & 15)) * 32 + ko];
    #pragma unroll
    for (int n = 0; n < 4; ++n) bfr[n] = *(const short8*)&Bl[(wc * 64 + n * 16 + (l & 15)) * 32 + ko];
    #pragma unroll
    for (int m = 0; m < 4; ++m)
      #pragma unroll
      for (int n = 0; n < 4; ++n)
        acc[m][n] = __builtin_amdgcn_mfma_f32_16x16x32_bf16(af[m], bfr[n], acc[m][n], 0, 0, 0);
    __syncthreads();
  }
  int cr = (l >> 4) * 4, cc = l & 15;
  #pragma unroll
  for (int m = 0; m < 4; ++m)
    #pragma unroll
    for (int n = 0; n < 4; ++n)
      #pragma unroll
      for (int r2 = 0; r2 < 4; ++r2) {
        int row = bm * 128 + wr * 64 + m * 16 + cr + r2;
        int col = bn * 128 + wc * 64 + n * 16 + cc;
        C[(size_t)row * 2048 + col] = f2bf(acc[m][n][r2]);
      }
}

// ---------------- per-(row,gate) U-path scalars ----------------------------
__global__ void k_scale(const u16* __restrict__ MXU, const float* __restrict__ xn2,
                        float* __restrict__ SU, float* __restrict__ UY2){
  int r = blockIdx.x, t = threadIdx.x;
  const u16* row = MXU + (size_t)r * 2048;
  uint4 q = *(const uint4*)(row + t * 8);
  float s = 0.f;
  s += bf2f(q.x & 0xffffu) * bf2f(q.x & 0xffffu) + bf2f(q.x >> 16) * bf2f(q.x >> 16);
  s += bf2f(q.y & 0xffffu) * bf2f(q.y & 0xffffu) + bf2f(q.y >> 16) * bf2f(q.y >> 16);
  s += bf2f(q.z & 0xffffu) * bf2f(q.z & 0xffffu) + bf2f(q.z >> 16) * bf2f(q.z >> 16);
  s += bf2f(q.w & 0xffffu) * bf2f(q.w & 0xffffu) + bf2f(q.w >> 16) * bf2f(q.w >> 16);
  s = wred(s);
  if ((t & 63) == 0) {
    int g = t >> 6;                         // wave == gate (64 thr * 8 el = 512)
    float mxn = fmaxf(sqrtf(s), MINN);
    float xn = fmaxf(sqrtf(xn2[r]), MINN);
    float tb = tanh_fast((mxn / xn) * artanh_c(xn));
    SU[r * 4 + g] = tb / mxn;
    UY2[r * 4 + g] = tb * tb;
  }
}

// ---------------- persistent scan: 1 block per batch, 128 steps ------------
__global__ void __launch_bounds__(1024) k_scan(
    const uint4* __restrict__ WG, const uint4* __restrict__ WDP,
    const u16* __restrict__ MXU, const float* __restrict__ SU, const float* __restrict__ UY2,
    const float* __restrict__ TS, const float* __restrict__ H0, const float* __restrict__ C0,
    float* __restrict__ OutO, float* __restrict__ OutH, float* __restrict__ OutC)
{
  const int b = blockIdx.x, t = threadIdx.x;
  const int lane = t & 63, wv = t >> 6;
  const int g = t >> 8;                    // gate of cols 2t,2t+1

  __shared__ __align__(16) u16 hph[512];
  __shared__ __align__(16) u16 cph[512];
  __shared__ float gbuf[2048];
  __shared__ float ubuf[512];
  __shared__ float tsb[128];
  __shared__ float pA_sq[16], pA_dt[16], pA_d[8];
  __shared__ float pB_us[8], pB_uc[8];
  __shared__ float pC0[8], pC1[8], pC2[8], pC3[8];
  __shared__ float pD0[8], pD1[8];
  __shared__ float scals[8];

  if (t < 128) tsb[t] = TS[b * 128 + t];
  float hv = 0.f, cv = 0.f;
  if (t < 512) {
    hv = H0[b * 512 + t]; cv = C0[b * 512 + t];
    hph[t] = f16b(hv); cph[t] = f16b(cv);
  }
  {
    float sh = wred(hv * hv), sc2 = wred(cv * cv);
    if (lane == 0 && wv < 8) { pB_us[wv] = sh; pB_uc[wv] = sc2; }
  }
  __syncthreads();
  float hn2 = 0.f, cn2 = 0.f;
  #pragma unroll
  for (int i = 0; i < 8; ++i) { hn2 += pB_us[i]; cn2 += pB_uc[i]; }
  float hn = fmaxf(sqrtf(hn2), MINN);
  float cn = fmaxf(sqrtf(cn2), MINN);

  const size_t outbase = (size_t)b * (128 * 512);

  for (int s = 0; s < 128; ++s) {
    const int row = b * 128 + s;
    // ---- loads for this step
    const u32 uxp = ((const u32*)(MXU + (size_t)row * 2048))[t];   // 2 bf16 of mxU
    if (t < 8) scals[t] = (t < 4) ? SU[row * 4 + t] : UY2[row * 4 + (t - 4)];
    const float ts_s = tsb[s];

    // ---- recurrent matvec: cols 2t,2t+1 of [h@W'| gates], col t of c@W'd
    float a0 = 0.f, a1 = 0.f, ad = 0.f;
    #pragma unroll 4
    for (int kp = 0; kp < 128; ++kp) {
      uint4 wq = WG[kp * 1024 + t];
      u32 hh0 = *(const u32*)&hph[4 * kp];
      u32 hh1 = *(const u32*)&hph[4 * kp + 2];
      a0 = fdot2_(wq.x, hh0, a0); a1 = fdot2_(wq.y, hh0, a1);
      a0 = fdot2_(wq.z, hh1, a0); a1 = fdot2_(wq.w, hh1, a1);
    }
    if (t < 512) {
      #pragma unroll 4
      for (int kq = 0; kq < 64; ++kq) {
        uint4 wq = WDP[kq * 512 + t];
        uint4 cc = *(const uint4*)&cph[8 * kq];
        ad = fdot2_(wq.x, cc.x, ad); ad = fdot2_(wq.y, cc.y, ad);
        ad = fdot2_(wq.z, cc.z, ad); ad = fdot2_(wq.w, cc.w, ad);
      }
    }
    const float ux0 = bf2f(uxp & 0xffffu), ux1 = bf2f(uxp >> 16);
    {
      float sq = wred(a0 * a0 + a1 * a1);
      float dt = wred(a0 * ux0 + a1 * ux1);
      float sd = wred(ad * ad);
      if (lane == 0) { pA_sq[wv] = sq; pA_dt[wv] = dt; if (wv < 8) pA_d[wv] = sd; }
    }
    __syncthreads();                                               // B1

    // ---- gate scalars (redundant per thread) + gate elementwise
    {
      float gsq = pA_sq[g * 4] + pA_sq[g * 4 + 1] + pA_sq[g * 4 + 2] + pA_sq[g * 4 + 3];
      float gdt = pA_dt[g * 4] + pA_dt[g * 4 + 1] + pA_dt[g * 4 + 2] + pA_dt[g * 4 + 3];
      float mxn = fmaxf(sqrtf(gsq), MINN);
      float tw = tanh_fast((mxn / hn) * artanh_c(hn));
      float x2 = tw * tw;
      float sw = tw / mxn;
      float su = scals[g], y2 = scals[4 + g];
      float xy = sw * su * gdt;
      float na = 1.f + 2.f * xy + y2, nb = 1.f - x2;
      float den = fmaxf(1.f + 2.f * xy + x2 * y2, MINN);
      float addn2 = fmaxf((na * na * x2 + 2.f * na * nb * xy + nb * nb * y2) / (den * den), 0.f);
      float an = fmaxf(sqrtf(addn2), MINN);
      float lam = artanh_c(an) / an;
      float GA = lam * na * sw / den, GB = lam * nb * su / den;
      float g0 = sigm(GA * a0 + GB * ux0);
      float g1 = sigm(GA * a1 + GB * ux1);
      gbuf[2 * t] = g0; gbuf[2 * t + 1] = g1;
      if (g == 2) {                                                // o gate -> output
        float2 o2; o2.x = g0; o2.y = g1;
        *(float2*)&OutO[outbase + (size_t)s * 512 + (2 * t - 1024)] = o2;
      }
    }
    // ---- d path: u = tanh(logmap0(mobius_matvec(W_d, c)))
    float uval = 0.f;
    if (t < 512) {
      float md2 = pA_d[0] + pA_d[1] + pA_d[2] + pA_d[3] + pA_d[4] + pA_d[5] + pA_d[6] + pA_d[7];
      float mdn = fmaxf(sqrtf(md2), MINN);
      float alc = tanh_fast((mdn / cn) * artanh_c(cn));
      float ycl = fmaxf(alc, MINN);
      float DS = (artanh_c(ycl) / ycl) * alc / mdn;
      uval = tanh_fast(DS * ad);
      ubuf[t] = uval;
    }
    {
      float us = wred(uval * uval);
      float uc = wred(uval * cv);
      if (lane == 0 && wv < 8) { pB_us[wv] = us; pB_uc[wv] = uc; }
    }
    __syncthreads();                                               // B3

    // ---- d-chain scalars (all threads, redundant)
    float usq = pB_us[0] + pB_us[1] + pB_us[2] + pB_us[3] + pB_us[4] + pB_us[5] + pB_us[6] + pB_us[7];
    float duc = pB_uc[0] + pB_uc[1] + pB_uc[2] + pB_uc[3] + pB_uc[4] + pB_uc[5] + pB_uc[6] + pB_uc[7];
    float un = fmaxf(sqrtf(usq), MINN);
    float t1 = tanh_fast(un);
    float at1 = artanh_c(t1);
    float k1 = t1 / un;
    float k2 = tanh_fast(ts_s * at1) / un;
    float x2l = t1 * t1;
    float xyl = -k1 * duc;
    float nal = 1.f + 2.f * xyl + cn2;
    float nbl = 1.f - x2l;
    float denl = fmaxf(1.f + 2.f * xyl + x2l * cn2, MINN);
    float p1 = -nal * k1 / denl, p2 = nbl / denl;
    float cl2 = fmaxf(p1 * p1 * usq + 2.f * p1 * p2 * duc + p2 * p2 * cn2, 0.f);
    float cs2n2 = k2 * k2 * usq;
    float xya = k2 * (p1 * usq + p2 * duc);
    float naa = 1.f + 2.f * xya + cs2n2;
    float nba = 1.f - cl2;
    float dena = fmaxf(1.f + 2.f * xya + cl2 * cs2n2, MINN);
    float r1 = (naa * p1 + nba * k2) / dena;
    float r2 = naa * p2 / dena;
    float cadj2 = fmaxf(r1 * r1 * usq + 2.f * r1 * r2 * duc + r2 * r2 * cn2, 0.f);

    // ---- gates combine (vector, t<512)
    float og = 0.f, cg = 0.f, wx1 = 0.f, wx2 = 0.f;
    if (t < 512) {
      float fg = gbuf[t], igv = gbuf[512 + t];
      og = gbuf[1024 + t]; cg = gbuf[1536 + t];
      float uu = ubuf[t];
      float cadj = r1 * uu + r2 * cv;
      wx1 = igv * cg;
      wx2 = fg * cadj;
    }
    {
      float s0 = wred(cg * cg), s1r = wred(wx1 * wx1), s2r = wred(wx2 * wx2), s3r = wred(wx1 * wx2);
      if (lane == 0 && wv < 8) { pC0[wv] = s0; pC1[wv] = s1r; pC2[wv] = s2r; pC3[wv] = s3r; }
    }
    __syncthreads();                                               // B5

    float Ssct = 0.f, Ssw1 = 0.f, Ssw2 = 0.f, Ss12 = 0.f;
    #pragma unroll
    for (int i = 0; i < 8; ++i) { Ssct += pC0[i]; Ssw1 += pC1[i]; Ssw2 += pC2[i]; Ss12 += pC3[i]; }
    float xnp = fmaxf(sqrtf(Ssct), MINN);
    float wxnp = fmaxf(sqrtf(Ssw1), MINN);
    float tp = tanh_fast((wxnp / xnp) * artanh_c(xnp));
    float s1c = tp / wxnp;
    float xnq = fmaxf(sqrtf(cadj2), MINN);
    float wxnq = fmaxf(sqrtf(Ssw2), MINN);
    float tq = tanh_fast((wxnq / xnq) * artanh_c(xnq));
    float s2c = tq / wxnq;
    float xyn = s1c * s2c * Ss12;
    float na2 = 1.f + 2.f * xyn + tq * tq;
    float nb2 = 1.f - tp * tp;
    float den2 = fmaxf(1.f + 2.f * xyn + tp * tp * tq * tq, MINN);
    float CA = na2 * s1c / den2, CB = nb2 * s2c / den2;
    cn2 = fmaxf((na2 * na2 * tp * tp + 2.f * na2 * nb2 * xyn + nb2 * nb2 * tq * tq) / (den2 * den2), 0.f);
    cn = fmaxf(sqrtf(cn2), MINN);

    // ---- c_new, v = tanh(c_new)
    float vv = 0.f, ov = 0.f;
    if (t < 512) {
      float cnew = CA * wx1 + CB * wx2;
      cv = cnew;
      cph[t] = f16b(cnew);
      vv = tanh_fast(cnew);
      ov = og * vv;
    }
    {
      float sv = wred(vv * vv), so = wred(ov * ov);
      if (lane == 0 && wv < 8) { pD0[wv] = sv; pD1[wv] = so; }
    }
    __syncthreads();                                               // B7

    float Ssv = 0.f, Sso = 0.f;
    #pragma unroll
    for (int i = 0; i < 8; ++i) { Ssv += pD0[i]; Sso += pD1[i]; }
    float vn = fmaxf(sqrtf(Ssv), MINN);
    float te = tanh_fast(vn);
    float ke = te / vn;
    float xnh = fmaxf(te, MINN);
    float wxnh = fmaxf(ke * sqrtf(Sso), MINN);
    float th = tanh_fast((wxnh / xnh) * artanh_c(xnh));
    float HS = (th / wxnh) * ke;
    hn = fmaxf(th, MINN);
    if (t < 512) {
      hv = HS * ov;
      hph[t] = f16b(hv);
    }
    __syncthreads();                                               // B9
  }
  if (t < 512) {
    OutH[b * 512 + t] = hv;
    OutC[b * 512 + t] = cv;
  }
}

extern "C" void kernel_launch(void* const* d_in, const int* in_sizes, int n_in,
                              void* d_out, int out_size, void* d_ws, size_t ws_size,
                              hipStream_t stream) {
  const float* inputs = (const float*)d_in[0];   // [64,128,512]
  const float* tsg    = (const float*)d_in[1];   // [64,128]
  const float* h0g    = (const float*)d_in[2];   // [64,512]
  const float* c0g    = (const float*)d_in[3];   // [64,512]
  const float* Wall   = (const float*)d_in[4];   // [512,2048]
  const float* Uall   = (const float*)d_in[5];   // [2048,512]
  const float* Wd     = (const float*)d_in[6];   // [512,512]
  char* ws = (char*)d_ws;

  uint4* WG   = (uint4*)(ws + 0);                // 128*1024*16 = 2 MB
  uint4* WDP  = (uint4*)(ws + 2097152);          // 64*512*16   = 512 KB
  u16*   XB   = (u16*)(ws + 2621440);            // 8192*512*2  = 8 MB
  u16*   UB   = (u16*)(ws + 11010048);           // 2048*512*2  = 2 MB
  u16*   MXU  = (u16*)(ws + 13107200);           // 8192*2048*2 = 32 MB
  float* XN2  = (float*)(ws + 46661632);         // 8192*4
  float* SU   = (float*)(ws + 46694400);         // 8192*4*4
  float* UY2  = (float*)(ws + 46825472);         // 8192*4*4

  float* out = (float*)d_out;
  float* out_o = out;                            // [64,128,512]
  float* out_h = out + 4194304;                  // [64,512]
  float* out_c = out + 4227072;                  // [64,512]

  k_pack_w<<<640, 256, 0, stream>>>(Wall, Wd, WG, WDP);
  k_convert_x<<<8192, 256, 0, stream>>>(inputs, XB, XN2);
  k_convert_u<<<4096, 256, 0, stream>>>(Uall, UB);
  k_gemm<<<dim3(16, 64), 256, 0, stream>>>(XB, UB, MXU);
  k_scale<<<8192, 256, 0, stream>>>(MXU, XN2, SU, UY2);
  k_scan<<<64, 1024, 0, stream>>>(WG, WDP, MXU, SU, UY2, tsg, h0g, c0g,
                                  out_o, out_h, out_c);
}